// Round 5
// baseline (397.184 us; speedup 1.0000x reference)
//
#include <hip/hip_runtime.h>

#define DIM 512
#define B_  64
#define L_  2048

typedef unsigned short u16;
typedef float f32x4 __attribute__((ext_vector_type(4)));
typedef short s16x8 __attribute__((ext_vector_type(8)));
typedef short s16x4 __attribute__((ext_vector_type(4)));

__device__ __forceinline__ u16 f2bf(float f) {
  union { float f; unsigned u; } x{f};
  unsigned r = x.u + 0x7FFFu + ((x.u >> 16) & 1u);
  return (u16)(r >> 16);
}

__device__ __forceinline__ float tanh_fast(float x) {
  float e2 = __expf(2.0f * x);
  return 1.0f - 2.0f / (e2 + 1.0f);
}

__device__ __forceinline__ s16x8 cvt8(f32x4 a, f32x4 b) {
  union { s16x8 h; unsigned u[4]; } r;
  asm("v_cvt_pk_bf16_f32 %0, %1, %2" : "=v"(r.u[0]) : "v"(a.x), "v"(a.y));
  asm("v_cvt_pk_bf16_f32 %0, %1, %2" : "=v"(r.u[1]) : "v"(a.z), "v"(a.w));
  asm("v_cvt_pk_bf16_f32 %0, %1, %2" : "=v"(r.u[2]) : "v"(b.x), "v"(b.y));
  asm("v_cvt_pk_bf16_f32 %0, %1, %2" : "=v"(r.u[3]) : "v"(b.z), "v"(b.w));
  return r.h;
}

// ---------- prep: q = query @ Wq^T + bq ; Wr -> bf16 transposed [t][o][32k] ----------
__global__ __launch_bounds__(256) void prep_kernel(
    const float* __restrict__ query, const float* __restrict__ Wq,
    const float* __restrict__ bq, const float* __restrict__ Wr,
    float* __restrict__ q_out, u16* __restrict__ Wrbt) {
  const int blk = blockIdx.x;
  const int tid = threadIdx.x;
  if (blk < 64) {
    __shared__ float qs[DIM];
    for (int i = tid; i < DIM; i += 256) qs[i] = query[blk * DIM + i];
    __syncthreads();
    for (int o = tid; o < DIM; o += 256) {
      const float* w = Wq + o * DIM;
      float acc = 0.f;
      for (int k = 0; k < DIM; k += 4) {
        f32x4 a = *(const f32x4*)&qs[k];
        f32x4 b = *(const f32x4*)&w[k];
        acc += a.x * b.x + a.y * b.y + a.z * b.z + a.w * b.w;
      }
      q_out[blk * DIM + o] = acc + bq[o];
    }
  } else {
    const int c = blk - 64;
    const int flat = c * 4096 + tid * 16;
    const int o = flat >> 9, k0 = flat & 511;
    const int t = k0 >> 5, kk = k0 & 31;
    u16* dst = Wrbt + t * 16384 + o * 32 + kk;
#pragma unroll
    for (int i = 0; i < 4; ++i) {
      f32x4 a = *(const f32x4*)&Wr[flat + i * 4];
      s16x4 o4;
      o4.x = (short)f2bf(a.x); o4.y = (short)f2bf(a.y);
      o4.z = (short)f2bf(a.z); o4.w = (short)f2bf(a.w);
      *(s16x4*)&dst[i * 4] = o4;
    }
  }
}

// ---------- pass 1: ref [L,B,D] f32 -> refT [b][t][l][32] bf16 ----------
// block (lc: 64, bc: 16): 32 l x 4 b slab; contiguous 8KB-stripe reads,
// contiguous 1KB-burst writes via LDS transpose.
__global__ __launch_bounds__(512) void transp_kernel(
    const float* __restrict__ ref, u16* __restrict__ refT) {
  __shared__ u16 S[4 * 32 * 520];  // 133,120 B; row pitch 520 u16
  const int lc = blockIdx.x, bc = blockIdx.y;
  const int l0 = lc * 32, b0 = bc * 4;
  const int tid = threadIdx.x;
  const int rb = tid >> 7, d4 = tid & 127;

#pragma unroll 4
  for (int l = 0; l < 32; ++l) {
    f32x4 a = *(const f32x4*)&ref[((size_t)(l0 + l) * 64 + b0 + rb) * 512 + d4 * 4];
    s16x4 o4;
    o4.x = (short)f2bf(a.x); o4.y = (short)f2bf(a.y);
    o4.z = (short)f2bf(a.z); o4.w = (short)f2bf(a.w);
    *(s16x4*)&S[(rb * 32 + l) * 520 + d4 * 4] = o4;
  }
  __syncthreads();
#pragma unroll 4
  for (int p = 0; p < 16; ++p) {
    const int g = p * 512 + tid;
    const int c = g & 3, l = (g >> 2) & 31, t = (g >> 7) & 15, b = g >> 11;
    s16x8 x = *(const s16x8*)&S[(b * 32 + l) * 520 + t * 32 + c * 8];
    *(s16x8*)&refT[(((size_t)(b0 + b) * 16 + t) * 2048 + l0 + l) * 32 + c * 8] = x;
  }
}

// ---------- pass 2: barrier-free streaming GEMM + fused epilogue ----------
// grid (16 lt, 64 b); 512 thr = 8 waves (4 ow x 2 lw), 128o x 64l each.
// A (Wrbt) L2-hot coalesced; B (refT bf16) contiguous-1KB waves, dbuf 1 ahead.
__global__ __launch_bounds__(512, 2) void gemm_main(
    const u16* __restrict__ refT, const u16* __restrict__ Wrbt,
    const float* __restrict__ q, const float* __restrict__ br,
    const float* __restrict__ v, float* __restrict__ e_out,
    float* __restrict__ logits) {
  __shared__ float u_lds[4][128];

  const int lt = blockIdx.x, b = blockIdx.y;
  const int l0 = lt * 128;
  const int tid = threadIdx.x, lane = tid & 63, w = tid >> 6;
  const int ow = w >> 1, lw = w & 1;
  const int rr = lane & 15, kg = lane >> 4;

  const u16* ap = Wrbt + (ow * 128 + rr) * 32 + kg * 8;
  const u16* bp = refT + ((size_t)b * 16 * 2048 + (size_t)(l0 + lw * 64 + rr)) * 32 + kg * 8;
  // per fn: +fn*16 rows = fn*512 u16 ; per t: +t*65536 u16

  s16x8 bcur[4], bnx[4];
#pragma unroll
  for (int fn = 0; fn < 4; ++fn) bcur[fn] = *(const s16x8*)(bp + fn * 512);

  f32x4 acc[8][4];
#pragma unroll
  for (int fm = 0; fm < 8; ++fm)
#pragma unroll
    for (int fn = 0; fn < 4; ++fn) acc[fm][fn] = (f32x4){0.f, 0.f, 0.f, 0.f};

#pragma unroll
  for (int t = 0; t < 16; ++t) {
    s16x8 af[8];
#pragma unroll
    for (int fm = 0; fm < 8; ++fm)
      af[fm] = *(const s16x8*)(ap + t * 16384 + fm * 512);
    if (t < 15) {
#pragma unroll
      for (int fn = 0; fn < 4; ++fn)
        bnx[fn] = *(const s16x8*)(bp + (t + 1) * 65536 + fn * 512);
    }
#pragma unroll
    for (int fm = 0; fm < 8; ++fm)
#pragma unroll
      for (int fn = 0; fn < 4; ++fn)
        acc[fm][fn] = __builtin_amdgcn_mfma_f32_16x16x32_bf16(bcur[fn], af[fm], acc[fm][fn], 0, 0, 0);
#pragma unroll
    for (int fn = 0; fn < 4; ++fn) bcur[fn] = bnx[fn];
  }

  // epilogue: e = acc + br ; u = sum_o v * tanh(acc + q + br). acc rows = l, cols = o.
  const int ob = ow * 128;
  f32x4 usA[4];
#pragma unroll
  for (int fn = 0; fn < 4; ++fn) usA[fn] = (f32x4){0.f, 0.f, 0.f, 0.f};
#pragma unroll
  for (int fm = 0; fm < 8; ++fm) {
    const int o = ob + fm * 16 + rr;
    const float brv = br[o];
    const float qv = q[b * DIM + o] + brv;
    const float vv = v[o];
    const size_t erow = ((size_t)(b * DIM + o)) * L_;
#pragma unroll
    for (int fn = 0; fn < 4; ++fn) {
      const int lb = l0 + lw * 64 + fn * 16 + kg * 4;
      f32x4 a = acc[fm][fn];
      f32x4 ev = a + brv;
      *(f32x4*)&e_out[erow + lb] = ev;  // plain store: let L2 combine 64B chunks
      f32x4 th;
      th.x = tanh_fast(a.x + qv);
      th.y = tanh_fast(a.y + qv);
      th.z = tanh_fast(a.z + qv);
      th.w = tanh_fast(a.w + qv);
      usA[fn] += vv * th;
    }
  }
#pragma unroll
  for (int fn = 0; fn < 4; ++fn) {
    f32x4 us = usA[fn];
#pragma unroll
    for (int msk = 1; msk <= 8; msk <<= 1) {
      us.x += __shfl_xor(us.x, msk);
      us.y += __shfl_xor(us.y, msk);
      us.z += __shfl_xor(us.z, msk);
      us.w += __shfl_xor(us.w, msk);
    }
    if (rr == 0)
      *(f32x4*)&u_lds[ow][lw * 64 + fn * 16 + kg * 4] = us;
  }
  __syncthreads();
  if (tid < 128)
    logits[(size_t)b * L_ + l0 + tid] =
        u_lds[0][tid] + u_lds[1][tid] + u_lds[2][tid] + u_lds[3][tid];
}

// ---------- fallback (round-4 kernel) if ws too small for refT ----------
__global__ __launch_bounds__(512, 2) void attn_main_fb(
    const float* __restrict__ ref, const u16* __restrict__ Wrbt,
    const float* __restrict__ q, const float* __restrict__ br,
    const float* __restrict__ v, float* __restrict__ e_out,
    float* __restrict__ logits) {
  __shared__ float u_lds[4][128];
  const int lt = blockIdx.x, b = blockIdx.y;
  const int l0 = lt * 128;
  const int tid = threadIdx.x, lane = tid & 63, w = tid >> 6;
  const int ow = w >> 1, lw = w & 1;
  const int rr = lane & 15, kg = lane >> 4;
  const float* refp[4];
#pragma unroll
  for (int fn = 0; fn < 4; ++fn)
    refp[fn] = ref + (size_t)(l0 + lw * 64 + fn * 16 + rr) * (B_ * DIM)
             + (size_t)b * DIM + kg * 8;
  const u16* ap = Wrbt + (ow * 128 + rr) * 32 + kg * 8;
  f32x4 rn[4][2];
#pragma unroll
  for (int fn = 0; fn < 4; ++fn) {
    rn[fn][0] = *(const f32x4*)(refp[fn]);
    rn[fn][1] = *(const f32x4*)(refp[fn] + 4);
  }
  f32x4 acc[8][4];
#pragma unroll
  for (int fm = 0; fm < 8; ++fm)
#pragma unroll
    for (int fn = 0; fn < 4; ++fn) acc[fm][fn] = (f32x4){0.f, 0.f, 0.f, 0.f};
  for (int t = 0; t < 16; ++t) {
    s16x8 af[8];
#pragma unroll
    for (int fm = 0; fm < 8; ++fm)
      af[fm] = *(const s16x8*)(ap + t * 16384 + fm * 512);
    s16x8 bf[4];
#pragma unroll
    for (int fn = 0; fn < 4; ++fn) bf[fn] = cvt8(rn[fn][0], rn[fn][1]);
    if (t < 15) {
#pragma unroll
      for (int fn = 0; fn < 4; ++fn) {
        rn[fn][0] = *(const f32x4*)(refp[fn] + (t + 1) * 32);
        rn[fn][1] = *(const f32x4*)(refp[fn] + (t + 1) * 32 + 4);
      }
    }
#pragma unroll
    for (int fm = 0; fm < 8; ++fm)
#pragma unroll
      for (int fn = 0; fn < 4; ++fn)
        acc[fm][fn] = __builtin_amdgcn_mfma_f32_16x16x32_bf16(bf[fn], af[fm], acc[fm][fn], 0, 0, 0);
  }
  const int ob = ow * 128;
  f32x4 usA[4];
#pragma unroll
  for (int fn = 0; fn < 4; ++fn) usA[fn] = (f32x4){0.f, 0.f, 0.f, 0.f};
#pragma unroll
  for (int fm = 0; fm < 8; ++fm) {
    const int o = ob + fm * 16 + rr;
    const float brv = br[o];
    const float qv = q[b * DIM + o] + brv;
    const float vv = v[o];
    const size_t erow = ((size_t)(b * DIM + o)) * L_;
#pragma unroll
    for (int fn = 0; fn < 4; ++fn) {
      const int lb = l0 + lw * 64 + fn * 16 + kg * 4;
      f32x4 a = acc[fm][fn];
      f32x4 ev = a + brv;
      __builtin_nontemporal_store(ev, (f32x4*)&e_out[erow + lb]);
      f32x4 th;
      th.x = tanh_fast(a.x + qv);
      th.y = tanh_fast(a.y + qv);
      th.z = tanh_fast(a.z + qv);
      th.w = tanh_fast(a.w + qv);
      usA[fn] += vv * th;
    }
  }
#pragma unroll
  for (int fn = 0; fn < 4; ++fn) {
    f32x4 us = usA[fn];
#pragma unroll
    for (int msk = 1; msk <= 8; msk <<= 1) {
      us.x += __shfl_xor(us.x, msk);
      us.y += __shfl_xor(us.y, msk);
      us.z += __shfl_xor(us.z, msk);
      us.w += __shfl_xor(us.w, msk);
    }
    if (rr == 0)
      *(f32x4*)&u_lds[ow][lw * 64 + fn * 16 + kg * 4] = us;
  }
  __syncthreads();
  if (tid < 128)
    logits[(size_t)b * L_ + l0 + tid] =
        u_lds[0][tid] + u_lds[1][tid] + u_lds[2][tid] + u_lds[3][tid];
}

extern "C" void kernel_launch(void* const* d_in, const int* in_sizes, int n_in,
                              void* d_out, int out_size, void* d_ws, size_t ws_size,
                              hipStream_t stream) {
  const float* query = (const float*)d_in[0];
  const float* ref   = (const float*)d_in[1];
  const float* Wq    = (const float*)d_in[2];
  const float* bq    = (const float*)d_in[3];
  const float* Wr    = (const float*)d_in[4];
  const float* br    = (const float*)d_in[5];
  const float* v     = (const float*)d_in[6];

  float* e_out  = (float*)d_out;
  float* logits = e_out + (size_t)B_ * DIM * L_;  // 67108864

  char* ws = (char*)d_ws;
  u16*   Wrbt = (u16*)ws;                         // 512 KB [16][512][32]
  float* q    = (float*)(ws + 524288);            // 128 KB
  u16*   refT = (u16*)(ws + 524288 + 131072);     // 134,217,728 B [64][16][2048][32]
  const size_t need = 524288 + 131072 + (size_t)B_ * 16 * 2048 * 32 * 2;

  prep_kernel<<<128, 256, 0, stream>>>(query, Wq, bq, Wr, q, Wrbt);
  if (ws_size >= need) {
    transp_kernel<<<dim3(64, 16), 512, 0, stream>>>(ref, refT);
    gemm_main<<<dim3(16, 64), 512, 0, stream>>>(refT, Wrbt, q, br, v, e_out, logits);
  } else {
    attn_main_fb<<<dim3(16, 64), 512, 0, stream>>>(ref, Wrbt, q, br, v, e_out, logits);
  }
}

// Round 6
// 379.916 us; speedup vs baseline: 1.0455x; 1.0455x over previous
//
#include <hip/hip_runtime.h>

#define DIM 512
#define B_  64
#define L_  2048

typedef unsigned short u16;
typedef float f32x4 __attribute__((ext_vector_type(4)));
typedef short s16x8 __attribute__((ext_vector_type(8)));
typedef short s16x4 __attribute__((ext_vector_type(4)));

__device__ __forceinline__ u16 f2bf(float f) {
  union { float f; unsigned u; } x{f};
  unsigned r = x.u + 0x7FFFu + ((x.u >> 16) & 1u);
  return (u16)(r >> 16);
}

__device__ __forceinline__ float tanh_fast(float x) {
  float e2 = __expf(2.0f * x);
  return 1.0f - 2.0f / (e2 + 1.0f);
}

__device__ __forceinline__ s16x8 cvt8(f32x4 a, f32x4 b) {
  union { s16x8 h; unsigned u[4]; } r;
  asm("v_cvt_pk_bf16_f32 %0, %1, %2" : "=v"(r.u[0]) : "v"(a.x), "v"(a.y));
  asm("v_cvt_pk_bf16_f32 %0, %1, %2" : "=v"(r.u[1]) : "v"(a.z), "v"(a.w));
  asm("v_cvt_pk_bf16_f32 %0, %1, %2" : "=v"(r.u[2]) : "v"(b.x), "v"(b.y));
  asm("v_cvt_pk_bf16_f32 %0, %1, %2" : "=v"(r.u[3]) : "v"(b.z), "v"(b.w));
  return r.h;
}

// ---------- prep: q = query @ Wq^T + bq ; Wr -> bf16 transposed [t][o][32k] ----------
__global__ __launch_bounds__(256) void prep_kernel(
    const float* __restrict__ query, const float* __restrict__ Wq,
    const float* __restrict__ bq, const float* __restrict__ Wr,
    float* __restrict__ q_out, u16* __restrict__ Wrbt) {
  const int blk = blockIdx.x;
  const int tid = threadIdx.x;
  if (blk < 64) {
    __shared__ float qs[DIM];
    for (int i = tid; i < DIM; i += 256) qs[i] = query[blk * DIM + i];
    __syncthreads();
    for (int o = tid; o < DIM; o += 256) {
      const float* w = Wq + o * DIM;
      float acc = 0.f;
      for (int k = 0; k < DIM; k += 4) {
        f32x4 a = *(const f32x4*)&qs[k];
        f32x4 b = *(const f32x4*)&w[k];
        acc += a.x * b.x + a.y * b.y + a.z * b.z + a.w * b.w;
      }
      q_out[blk * DIM + o] = acc + bq[o];
    }
  } else {
    const int c = blk - 64;
    const int flat = c * 4096 + tid * 16;
    const int o = flat >> 9, k0 = flat & 511;
    const int t = k0 >> 5, kk = k0 & 31;
    u16* dst = Wrbt + t * 16384 + o * 32 + kk;
#pragma unroll
    for (int i = 0; i < 4; ++i) {
      f32x4 a = *(const f32x4*)&Wr[flat + i * 4];
      s16x4 o4;
      o4.x = (short)f2bf(a.x); o4.y = (short)f2bf(a.y);
      o4.z = (short)f2bf(a.z); o4.w = (short)f2bf(a.w);
      *(s16x4*)&dst[i * 4] = o4;
    }
  }
}

// ---------- pass 1: ref [L,B,D] f32 -> refT [b][t][l][32] bf16 ----------
// LDS at 16B-unit granularity, pitch 65 units/row, col16 ^= (l&7)<<2 swizzle
// (bank-group = (row + col16') % 8 -> uniform 8 lanes/group both phases).
__global__ __launch_bounds__(512) void transp_kernel(
    const float* __restrict__ ref, u16* __restrict__ refT) {
  __shared__ u16 S[128 * 520];  // 128 rows x 65 units x 16B = 133,120 B
  const int lc = blockIdx.x, bc = blockIdx.y;
  const int l0 = lc * 32, b0 = bc * 4;
  const int tid = threadIdx.x;
  const int rb = tid >> 7, d4 = tid & 127;

#pragma unroll 4
  for (int l = 0; l < 32; ++l) {
    f32x4 a = *(const f32x4*)&ref[((size_t)(l0 + l) * 64 + b0 + rb) * 512 + d4 * 4];
    s16x4 o4;
    o4.x = (short)f2bf(a.x); o4.y = (short)f2bf(a.y);
    o4.z = (short)f2bf(a.z); o4.w = (short)f2bf(a.w);
    const int unit = (rb * 32 + l) * 65 + ((d4 >> 1) ^ ((l & 7) << 2));
    *(s16x4*)&S[(unit << 3) + ((d4 & 1) << 2)] = o4;
  }
  __syncthreads();
#pragma unroll 4
  for (int p = 0; p < 16; ++p) {
    const int g = p * 512 + tid;
    const int c = g & 3, l = (g >> 2) & 31, t = (g >> 7) & 15, b = g >> 11;
    const int unit = (b * 32 + l) * 65 + ((t * 4 + c) ^ ((l & 7) << 2));
    s16x8 x = *(const s16x8*)&S[unit << 3];
    *(s16x8*)&refT[(((size_t)(b0 + b) * 16 + t) * 2048 + l0 + l) * 32 + c * 8] = x;
  }
}

// ---------- pass 2: streaming GEMM + fused epilogue, 128o x 512l tiles ----------
// 1024 blocks; bijective remap puts the 4 lt-blocks of each (ot,b) on ONE XCD
// in the same dispatch round -> L2 assembles full 8KB e-rows before eviction.
// 8 waves each own 128o x 64l (acc[8][4], identical frag math to round 5).
__global__ __launch_bounds__(512, 2) void gemm_main(
    const u16* __restrict__ refT, const u16* __restrict__ Wrbt,
    const float* __restrict__ q, const float* __restrict__ br,
    const float* __restrict__ v, float* __restrict__ e_out,
    float* __restrict__ upart) {
  const int idx = blockIdx.x;
  const int xcd = idx & 7, slot = idx >> 3;
  const int lt = slot & 3;
  const int gg = xcd + ((slot >> 2) << 3);   // 0..255
  const int ot = gg & 3, b = gg >> 2;

  const int tid = threadIdx.x, lane = tid & 63, w = tid >> 6;
  const int rr = lane & 15, kg = lane >> 4;

  const u16* ap = Wrbt + (ot * 128 + rr) * 32 + kg * 8;
  const u16* bp = refT + ((size_t)b * 16 * 2048 + (size_t)(lt * 512 + w * 64 + rr)) * 32 + kg * 8;

  s16x8 bcur[4], bnx[4];
#pragma unroll
  for (int fn = 0; fn < 4; ++fn) bcur[fn] = *(const s16x8*)(bp + fn * 512);

  f32x4 acc[8][4];
#pragma unroll
  for (int fm = 0; fm < 8; ++fm)
#pragma unroll
    for (int fn = 0; fn < 4; ++fn) acc[fm][fn] = (f32x4){0.f, 0.f, 0.f, 0.f};

#pragma unroll
  for (int t = 0; t < 16; ++t) {
    s16x8 af[8];
#pragma unroll
    for (int fm = 0; fm < 8; ++fm)
      af[fm] = *(const s16x8*)(ap + t * 16384 + fm * 512);
    if (t < 15) {
#pragma unroll
      for (int fn = 0; fn < 4; ++fn)
        bnx[fn] = *(const s16x8*)(bp + (t + 1) * 65536 + fn * 512);
    }
#pragma unroll
    for (int fm = 0; fm < 8; ++fm)
#pragma unroll
      for (int fn = 0; fn < 4; ++fn)
        acc[fm][fn] = __builtin_amdgcn_mfma_f32_16x16x32_bf16(bcur[fn], af[fm], acc[fm][fn], 0, 0, 0);
#pragma unroll
    for (int fn = 0; fn < 4; ++fn) bcur[fn] = bnx[fn];
  }

  // epilogue: e = acc + br ; u-partial = sum_{o in ot-range} v * tanh(acc + q + br)
  f32x4 usA[4];
#pragma unroll
  for (int fn = 0; fn < 4; ++fn) usA[fn] = (f32x4){0.f, 0.f, 0.f, 0.f};
#pragma unroll
  for (int fm = 0; fm < 8; ++fm) {
    const int o = ot * 128 + fm * 16 + rr;
    const float brv = br[o];
    const float qv = q[b * DIM + o] + brv;
    const float vv = v[o];
    const size_t erow = ((size_t)(b * DIM + o)) * L_;
#pragma unroll
    for (int fn = 0; fn < 4; ++fn) {
      const int lb = lt * 512 + w * 64 + fn * 16 + kg * 4;
      f32x4 a = acc[fm][fn];
      f32x4 ev = a + brv;
      *(f32x4*)&e_out[erow + lb] = ev;  // plain store: L2 assembles full rows
      f32x4 th;
      th.x = tanh_fast(a.x + qv);
      th.y = tanh_fast(a.y + qv);
      th.z = tanh_fast(a.z + qv);
      th.w = tanh_fast(a.w + qv);
      usA[fn] += vv * th;
    }
  }
#pragma unroll
  for (int fn = 0; fn < 4; ++fn) {
    f32x4 us = usA[fn];
#pragma unroll
    for (int msk = 1; msk <= 8; msk <<= 1) {  // reduce over rr lanes (o dim)
      us.x += __shfl_xor(us.x, msk);
      us.y += __shfl_xor(us.y, msk);
      us.z += __shfl_xor(us.z, msk);
      us.w += __shfl_xor(us.w, msk);
    }
    if (rr == 0)
      *(f32x4*)&upart[(size_t)((ot << 6) + b) * L_ + lt * 512 + w * 64 + fn * 16 + kg * 4] = us;
  }
}

// ---------- reduce 4 o-tile partials -> logits ----------
__global__ __launch_bounds__(256) void ured_kernel(
    const float* __restrict__ up, float* __restrict__ out) {
  const int idx = blockIdx.x * 256 + threadIdx.x;
  out[idx] = up[idx] + up[idx + 131072] + up[idx + 262144] + up[idx + 393216];
}

// ---------- fallback (round-4 kernel) if ws too small for refT ----------
__global__ __launch_bounds__(512, 2) void attn_main_fb(
    const float* __restrict__ ref, const u16* __restrict__ Wrbt,
    const float* __restrict__ q, const float* __restrict__ br,
    const float* __restrict__ v, float* __restrict__ e_out,
    float* __restrict__ logits) {
  __shared__ float u_lds[4][128];
  const int lt = blockIdx.x, b = blockIdx.y;
  const int l0 = lt * 128;
  const int tid = threadIdx.x, lane = tid & 63, w = tid >> 6;
  const int ow = w >> 1, lw = w & 1;
  const int rr = lane & 15, kg = lane >> 4;
  const float* refp[4];
#pragma unroll
  for (int fn = 0; fn < 4; ++fn)
    refp[fn] = ref + (size_t)(l0 + lw * 64 + fn * 16 + rr) * (B_ * DIM)
             + (size_t)b * DIM + kg * 8;
  const u16* ap = Wrbt + (ow * 128 + rr) * 32 + kg * 8;
  f32x4 rn[4][2];
#pragma unroll
  for (int fn = 0; fn < 4; ++fn) {
    rn[fn][0] = *(const f32x4*)(refp[fn]);
    rn[fn][1] = *(const f32x4*)(refp[fn] + 4);
  }
  f32x4 acc[8][4];
#pragma unroll
  for (int fm = 0; fm < 8; ++fm)
#pragma unroll
    for (int fn = 0; fn < 4; ++fn) acc[fm][fn] = (f32x4){0.f, 0.f, 0.f, 0.f};
  for (int t = 0; t < 16; ++t) {
    s16x8 af[8];
#pragma unroll
    for (int fm = 0; fm < 8; ++fm)
      af[fm] = *(const s16x8*)(ap + t * 16384 + fm * 512);
    s16x8 bf[4];
#pragma unroll
    for (int fn = 0; fn < 4; ++fn) bf[fn] = cvt8(rn[fn][0], rn[fn][1]);
    if (t < 15) {
#pragma unroll
      for (int fn = 0; fn < 4; ++fn) {
        rn[fn][0] = *(const f32x4*)(refp[fn] + (t + 1) * 32);
        rn[fn][1] = *(const f32x4*)(refp[fn] + (t + 1) * 32 + 4);
      }
    }
#pragma unroll
    for (int fm = 0; fm < 8; ++fm)
#pragma unroll
      for (int fn = 0; fn < 4; ++fn)
        acc[fm][fn] = __builtin_amdgcn_mfma_f32_16x16x32_bf16(bf[fn], af[fm], acc[fm][fn], 0, 0, 0);
  }
  const int ob = ow * 128;
  f32x4 usA[4];
#pragma unroll
  for (int fn = 0; fn < 4; ++fn) usA[fn] = (f32x4){0.f, 0.f, 0.f, 0.f};
#pragma unroll
  for (int fm = 0; fm < 8; ++fm) {
    const int o = ob + fm * 16 + rr;
    const float brv = br[o];
    const float qv = q[b * DIM + o] + brv;
    const float vv = v[o];
    const size_t erow = ((size_t)(b * DIM + o)) * L_;
#pragma unroll
    for (int fn = 0; fn < 4; ++fn) {
      const int lb = l0 + lw * 64 + fn * 16 + kg * 4;
      f32x4 a = acc[fm][fn];
      f32x4 ev = a + brv;
      __builtin_nontemporal_store(ev, (f32x4*)&e_out[erow + lb]);
      f32x4 th;
      th.x = tanh_fast(a.x + qv);
      th.y = tanh_fast(a.y + qv);
      th.z = tanh_fast(a.z + qv);
      th.w = tanh_fast(a.w + qv);
      usA[fn] += vv * th;
    }
  }
#pragma unroll
  for (int fn = 0; fn < 4; ++fn) {
    f32x4 us = usA[fn];
#pragma unroll
    for (int msk = 1; msk <= 8; msk <<= 1) {
      us.x += __shfl_xor(us.x, msk);
      us.y += __shfl_xor(us.y, msk);
      us.z += __shfl_xor(us.z, msk);
      us.w += __shfl_xor(us.w, msk);
    }
    if (rr == 0)
      *(f32x4*)&u_lds[ow][lw * 64 + fn * 16 + kg * 4] = us;
  }
  __syncthreads();
  if (tid < 128)
    logits[(size_t)b * L_ + l0 + tid] =
        u_lds[0][tid] + u_lds[1][tid] + u_lds[2][tid] + u_lds[3][tid];
}

extern "C" void kernel_launch(void* const* d_in, const int* in_sizes, int n_in,
                              void* d_out, int out_size, void* d_ws, size_t ws_size,
                              hipStream_t stream) {
  const float* query = (const float*)d_in[0];
  const float* ref   = (const float*)d_in[1];
  const float* Wq    = (const float*)d_in[2];
  const float* bq    = (const float*)d_in[3];
  const float* Wr    = (const float*)d_in[4];
  const float* br    = (const float*)d_in[5];
  const float* v     = (const float*)d_in[6];

  float* e_out  = (float*)d_out;
  float* logits = e_out + (size_t)B_ * DIM * L_;  // 67108864

  char* ws = (char*)d_ws;
  u16*   Wrbt  = (u16*)ws;                                  // 512 KB [16][512][32]
  float* q     = (float*)(ws + 524288);                     // 128 KB
  u16*   refT  = (u16*)(ws + 524288 + 131072);              // 134,217,728 B
  float* upart = (float*)(ws + 524288 + 131072 + 134217728);// 2 MB
  const size_t need = 524288 + 131072 + 134217728 + 2097152;

  prep_kernel<<<128, 256, 0, stream>>>(query, Wq, bq, Wr, q, Wrbt);
  if (ws_size >= need) {
    transp_kernel<<<dim3(64, 16), 512, 0, stream>>>(ref, refT);
    gemm_main<<<1024, 512, 0, stream>>>(refT, Wrbt, q, br, v, e_out, upart);
    ured_kernel<<<512, 256, 0, stream>>>(upart, logits);
  } else {
    attn_main_fb<<<dim3(16, 64), 512, 0, stream>>>(ref, Wrbt, q, br, v, e_out, logits);
  }
}

// Round 7
// 348.909 us; speedup vs baseline: 1.1384x; 1.0889x over previous
//
#include <hip/hip_runtime.h>

#define DIM 512
#define B_  64
#define L_  2048

typedef unsigned short u16;
typedef float f32x4 __attribute__((ext_vector_type(4)));
typedef short s16x8 __attribute__((ext_vector_type(8)));
typedef short s16x4 __attribute__((ext_vector_type(4)));

__device__ __forceinline__ u16 f2bf(float f) {
  union { float f; unsigned u; } x{f};
  unsigned r = x.u + 0x7FFFu + ((x.u >> 16) & 1u);
  return (u16)(r >> 16);
}

__device__ __forceinline__ float tanh_fast(float x) {
  float e2 = __expf(2.0f * x);
  return 1.0f - 2.0f / (e2 + 1.0f);
}

__device__ __forceinline__ s16x8 cvt8(f32x4 a, f32x4 b) {
  union { s16x8 h; unsigned u[4]; } r;
  asm("v_cvt_pk_bf16_f32 %0, %1, %2" : "=v"(r.u[0]) : "v"(a.x), "v"(a.y));
  asm("v_cvt_pk_bf16_f32 %0, %1, %2" : "=v"(r.u[1]) : "v"(a.z), "v"(a.w));
  asm("v_cvt_pk_bf16_f32 %0, %1, %2" : "=v"(r.u[2]) : "v"(b.x), "v"(b.y));
  asm("v_cvt_pk_bf16_f32 %0, %1, %2" : "=v"(r.u[3]) : "v"(b.z), "v"(b.w));
  return r.h;
}

// ---------- prep: q = query @ Wq^T + bq ; Wr -> bf16 transposed [t][o][32k] ----------
__global__ __launch_bounds__(256) void prep_kernel(
    const float* __restrict__ query, const float* __restrict__ Wq,
    const float* __restrict__ bq, const float* __restrict__ Wr,
    float* __restrict__ q_out, u16* __restrict__ Wrbt) {
  const int blk = blockIdx.x;
  const int tid = threadIdx.x;
  if (blk < 64) {
    __shared__ float qs[DIM];
    for (int i = tid; i < DIM; i += 256) qs[i] = query[blk * DIM + i];
    __syncthreads();
    for (int o = tid; o < DIM; o += 256) {
      const float* w = Wq + o * DIM;
      float acc = 0.f;
      for (int k = 0; k < DIM; k += 4) {
        f32x4 a = *(const f32x4*)&qs[k];
        f32x4 b = *(const f32x4*)&w[k];
        acc += a.x * b.x + a.y * b.y + a.z * b.z + a.w * b.w;
      }
      q_out[blk * DIM + o] = acc + bq[o];
    }
  } else {
    const int c = blk - 64;
    const int flat = c * 4096 + tid * 16;
    const int o = flat >> 9, k0 = flat & 511;
    const int t = k0 >> 5, kk = k0 & 31;
    u16* dst = Wrbt + t * 16384 + o * 32 + kk;
#pragma unroll
    for (int i = 0; i < 4; ++i) {
      f32x4 a = *(const f32x4*)&Wr[flat + i * 4];
      s16x4 o4;
      o4.x = (short)f2bf(a.x); o4.y = (short)f2bf(a.y);
      o4.z = (short)f2bf(a.z); o4.w = (short)f2bf(a.w);
      *(s16x4*)&dst[i * 4] = o4;
    }
  }
}

// ---------- pass 1: ref [L,B,D] f32 -> refT [b][t][l][32] bf16 ----------
// 1b x 32l tile: LDS 33 KB -> 4 blocks/CU (16 waves/CU). Verified swizzle
// (16B units, pitch 65, col ^= (l&7)<<2).
__global__ __launch_bounds__(256) void transp_kernel(
    const float* __restrict__ ref, u16* __restrict__ refT) {
  __shared__ u16 S[32 * 520];  // 33,280 B
  const int lc = blockIdx.x, b = blockIdx.y;
  const int l0 = lc * 32;
  const int tid = threadIdx.x;
  const int d4 = tid & 127;

#pragma unroll 4
  for (int p = 0; p < 16; ++p) {
    const int row = p * 2 + (tid >> 7);
    f32x4 a = *(const f32x4*)&ref[((size_t)(l0 + row) * 64 + b) * 512 + d4 * 4];
    s16x4 o4;
    o4.x = (short)f2bf(a.x); o4.y = (short)f2bf(a.y);
    o4.z = (short)f2bf(a.z); o4.w = (short)f2bf(a.w);
    const int unit = row * 65 + ((d4 >> 1) ^ ((row & 7) << 2));
    *(s16x4*)&S[(unit << 3) + ((d4 & 1) << 2)] = o4;
  }
  __syncthreads();
#pragma unroll 4
  for (int p = 0; p < 8; ++p) {
    const int g = p * 256 + tid;
    const int c = g & 3, l = (g >> 2) & 31, t = g >> 7;
    const int unit = l * 65 + ((t * 4 + c) ^ ((l & 7) << 2));
    s16x8 x = *(const s16x8*)&S[unit << 3];
    *(s16x8*)&refT[(((size_t)b * 16 + t) * 2048 + l0 + l) * 32 + c * 8] = x;
  }
}

// ---------- pass 2: GEMM + fused epilogue, block = 512o x 32l ----------
// 8 waves, each 64o x 32l (acc[4][2] = 32 regs -> 128-reg tier, 16 waves/CU).
// B-strip (32KB) staged to LDS once; K-loop barrier-free: A global (L2-hot,
// prefetch 1 ahead), B ds_read (pitch 520 -> uniform banks). Logits in-block.
__global__ __launch_bounds__(512, 4) void gemm_main(
    const u16* __restrict__ refT, const u16* __restrict__ Wrbt,
    const float* __restrict__ q, const float* __restrict__ br,
    const float* __restrict__ v, float* __restrict__ e_out,
    float* __restrict__ logits) {
  __shared__ u16 Bs[32][520];     // 33,280 B
  __shared__ float u_lds[8][32];

  const int lc = blockIdx.x, b = blockIdx.y;
  const int l0 = lc * 32;
  const int tid = threadIdx.x, lane = tid & 63, w = tid >> 6;
  const int rr = lane & 15, kg = lane >> 4;

  // stage B strip: 32l x 512k bf16 = 2048 s16x8, 4 per thread, coalesced 1KB/wave
#pragma unroll
  for (int p = 0; p < 4; ++p) {
    const int g = p * 512 + tid;
    const int c = g & 3, l = (g >> 2) & 31, t = g >> 7;
    s16x8 x = *(const s16x8*)&refT[(((size_t)b * 16 + t) * 2048 + l0 + l) * 32 + c * 8];
    *(s16x8*)&Bs[l][t * 32 + c * 8] = x;
  }
  __syncthreads();

  const u16* ap = Wrbt + (w * 64 + rr) * 32 + kg * 8;

  f32x4 acc[4][2];
#pragma unroll
  for (int fm = 0; fm < 4; ++fm)
#pragma unroll
    for (int fn = 0; fn < 2; ++fn) acc[fm][fn] = (f32x4){0.f, 0.f, 0.f, 0.f};

  s16x8 acur[4], anx[4];
#pragma unroll
  for (int fm = 0; fm < 4; ++fm)
    acur[fm] = *(const s16x8*)(ap + fm * 512);

#pragma unroll
  for (int t = 0; t < 16; ++t) {
    if (t < 15) {
#pragma unroll
      for (int fm = 0; fm < 4; ++fm)
        anx[fm] = *(const s16x8*)(ap + (t + 1) * 16384 + fm * 512);
    }
    s16x8 bf[2];
#pragma unroll
    for (int fn = 0; fn < 2; ++fn)
      bf[fn] = *(const s16x8*)&Bs[fn * 16 + rr][t * 32 + kg * 8];
#pragma unroll
    for (int fm = 0; fm < 4; ++fm)
#pragma unroll
      for (int fn = 0; fn < 2; ++fn)
        acc[fm][fn] = __builtin_amdgcn_mfma_f32_16x16x32_bf16(bf[fn], acur[fm], acc[fm][fn], 0, 0, 0);
#pragma unroll
    for (int fm = 0; fm < 4; ++fm) acur[fm] = anx[fm];
  }

  // epilogue: e = acc + br ; u = sum_o v * tanh(acc + q + br). acc rows=l, cols=o.
  f32x4 usA[2];
#pragma unroll
  for (int fn = 0; fn < 2; ++fn) usA[fn] = (f32x4){0.f, 0.f, 0.f, 0.f};
#pragma unroll
  for (int fm = 0; fm < 4; ++fm) {
    const int o = w * 64 + fm * 16 + rr;
    const float brv = br[o];
    const float qv = q[b * DIM + o] + brv;
    const float vv = v[o];
    const size_t erow = ((size_t)(b * DIM + o)) * L_;
#pragma unroll
    for (int fn = 0; fn < 2; ++fn) {
      const int lb = l0 + fn * 16 + kg * 4;
      f32x4 a = acc[fm][fn];
      f32x4 ev = a + brv;
      *(f32x4*)&e_out[erow + lb] = ev;
      f32x4 th;
      th.x = tanh_fast(a.x + qv);
      th.y = tanh_fast(a.y + qv);
      th.z = tanh_fast(a.z + qv);
      th.w = tanh_fast(a.w + qv);
      usA[fn] += vv * th;
    }
  }
#pragma unroll
  for (int fn = 0; fn < 2; ++fn) {
    f32x4 us = usA[fn];
#pragma unroll
    for (int msk = 1; msk <= 8; msk <<= 1) {  // reduce over rr (o dim)
      us.x += __shfl_xor(us.x, msk);
      us.y += __shfl_xor(us.y, msk);
      us.z += __shfl_xor(us.z, msk);
      us.w += __shfl_xor(us.w, msk);
    }
    if (rr == 0)
      *(f32x4*)&u_lds[w][fn * 16 + kg * 4] = us;
  }
  __syncthreads();
  if (tid < 32) {
    float s = 0.f;
#pragma unroll
    for (int ww = 0; ww < 8; ++ww) s += u_lds[ww][tid];
    logits[(size_t)b * L_ + l0 + tid] = s;
  }
}

// ---------- fallback (round-4 kernel) if ws too small for refT ----------
__global__ __launch_bounds__(512, 2) void attn_main_fb(
    const float* __restrict__ ref, const u16* __restrict__ Wrbt,
    const float* __restrict__ q, const float* __restrict__ br,
    const float* __restrict__ v, float* __restrict__ e_out,
    float* __restrict__ logits) {
  __shared__ float u_lds[4][128];
  const int lt = blockIdx.x, b = blockIdx.y;
  const int l0 = lt * 128;
  const int tid = threadIdx.x, lane = tid & 63, w = tid >> 6;
  const int ow = w >> 1, lw = w & 1;
  const int rr = lane & 15, kg = lane >> 4;
  const float* refp[4];
#pragma unroll
  for (int fn = 0; fn < 4; ++fn)
    refp[fn] = ref + (size_t)(l0 + lw * 64 + fn * 16 + rr) * (B_ * DIM)
             + (size_t)b * DIM + kg * 8;
  const u16* ap = Wrbt + (ow * 128 + rr) * 32 + kg * 8;
  f32x4 rn[4][2];
#pragma unroll
  for (int fn = 0; fn < 4; ++fn) {
    rn[fn][0] = *(const f32x4*)(refp[fn]);
    rn[fn][1] = *(const f32x4*)(refp[fn] + 4);
  }
  f32x4 acc[8][4];
#pragma unroll
  for (int fm = 0; fm < 8; ++fm)
#pragma unroll
    for (int fn = 0; fn < 4; ++fn) acc[fm][fn] = (f32x4){0.f, 0.f, 0.f, 0.f};
  for (int t = 0; t < 16; ++t) {
    s16x8 af[8];
#pragma unroll
    for (int fm = 0; fm < 8; ++fm)
      af[fm] = *(const s16x8*)(ap + t * 16384 + fm * 512);
    s16x8 bf[4];
#pragma unroll
    for (int fn = 0; fn < 4; ++fn) bf[fn] = cvt8(rn[fn][0], rn[fn][1]);
    if (t < 15) {
#pragma unroll
      for (int fn = 0; fn < 4; ++fn) {
        rn[fn][0] = *(const f32x4*)(refp[fn] + (t + 1) * 32);
        rn[fn][1] = *(const f32x4*)(refp[fn] + (t + 1) * 32 + 4);
      }
    }
#pragma unroll
    for (int fm = 0; fm < 8; ++fm)
#pragma unroll
      for (int fn = 0; fn < 4; ++fn)
        acc[fm][fn] = __builtin_amdgcn_mfma_f32_16x16x32_bf16(bf[fn], af[fm], acc[fm][fn], 0, 0, 0);
  }
  const int ob = ow * 128;
  f32x4 usA[4];
#pragma unroll
  for (int fn = 0; fn < 4; ++fn) usA[fn] = (f32x4){0.f, 0.f, 0.f, 0.f};
#pragma unroll
  for (int fm = 0; fm < 8; ++fm) {
    const int o = ob + fm * 16 + rr;
    const float brv = br[o];
    const float qv = q[b * DIM + o] + brv;
    const float vv = v[o];
    const size_t erow = ((size_t)(b * DIM + o)) * L_;
#pragma unroll
    for (int fn = 0; fn < 4; ++fn) {
      const int lb = l0 + lw * 64 + fn * 16 + kg * 4;
      f32x4 a = acc[fm][fn];
      f32x4 ev = a + brv;
      __builtin_nontemporal_store(ev, (f32x4*)&e_out[erow + lb]);
      f32x4 th;
      th.x = tanh_fast(a.x + qv);
      th.y = tanh_fast(a.y + qv);
      th.z = tanh_fast(a.z + qv);
      th.w = tanh_fast(a.w + qv);
      usA[fn] += vv * th;
    }
  }
#pragma unroll
  for (int fn = 0; fn < 4; ++fn) {
    f32x4 us = usA[fn];
#pragma unroll
    for (int msk = 1; msk <= 8; msk <<= 1) {
      us.x += __shfl_xor(us.x, msk);
      us.y += __shfl_xor(us.y, msk);
      us.z += __shfl_xor(us.z, msk);
      us.w += __shfl_xor(us.w, msk);
    }
    if (rr == 0)
      *(f32x4*)&u_lds[ow][lw * 64 + fn * 16 + kg * 4] = us;
  }
  __syncthreads();
  if (tid < 128)
    logits[(size_t)b * L_ + l0 + tid] =
        u_lds[0][tid] + u_lds[1][tid] + u_lds[2][tid] + u_lds[3][tid];
}

extern "C" void kernel_launch(void* const* d_in, const int* in_sizes, int n_in,
                              void* d_out, int out_size, void* d_ws, size_t ws_size,
                              hipStream_t stream) {
  const float* query = (const float*)d_in[0];
  const float* ref   = (const float*)d_in[1];
  const float* Wq    = (const float*)d_in[2];
  const float* bq    = (const float*)d_in[3];
  const float* Wr    = (const float*)d_in[4];
  const float* br    = (const float*)d_in[5];
  const float* v     = (const float*)d_in[6];

  float* e_out  = (float*)d_out;
  float* logits = e_out + (size_t)B_ * DIM * L_;  // 67108864

  char* ws = (char*)d_ws;
  u16*   Wrbt = (u16*)ws;                         // 512 KB [16][512][32]
  float* q    = (float*)(ws + 524288);            // 128 KB
  u16*   refT = (u16*)(ws + 524288 + 131072);     // 134,217,728 B [64][16][2048][32]
  const size_t need = 524288 + 131072 + 134217728;

  prep_kernel<<<128, 256, 0, stream>>>(query, Wq, bq, Wr, q, Wrbt);
  if (ws_size >= need) {
    transp_kernel<<<dim3(64, 64), 256, 0, stream>>>(ref, refT);
    gemm_main<<<dim3(64, 64), 512, 0, stream>>>(refT, Wrbt, q, br, v, e_out, logits);
  } else {
    attn_main_fb<<<dim3(16, 64), 512, 0, stream>>>(ref, Wrbt, q, br, v, e_out, logits);
  }
}

// Round 8
// 242.259 us; speedup vs baseline: 1.6395x; 1.4402x over previous
//
#include <hip/hip_runtime.h>

#define DIM 512
#define B_  64
#define L_  2048

typedef unsigned short u16;
typedef float f32x4 __attribute__((ext_vector_type(4)));
typedef short s16x8 __attribute__((ext_vector_type(8)));
typedef short s16x4 __attribute__((ext_vector_type(4)));

__device__ __forceinline__ u16 f2bf(float f) {
  union { float f; unsigned u; } x{f};
  unsigned r = x.u + 0x7FFFu + ((x.u >> 16) & 1u);
  return (u16)(r >> 16);
}

__device__ __forceinline__ float tanh_fast(float x) {
  float e2 = __expf(2.0f * x);
  return 1.0f - 2.0f / (e2 + 1.0f);
}

// ---------- prep: q = query @ Wq^T + bq ; Wr -> bf16 transposed [t][o][32k] ----------
__global__ __launch_bounds__(256) void prep_kernel(
    const float* __restrict__ query, const float* __restrict__ Wq,
    const float* __restrict__ bq, const float* __restrict__ Wr,
    float* __restrict__ q_out, u16* __restrict__ Wrbt) {
  const int blk = blockIdx.x;
  const int tid = threadIdx.x;
  if (blk < 64) {
    __shared__ float qs[DIM];
    for (int i = tid; i < DIM; i += 256) qs[i] = query[blk * DIM + i];
    __syncthreads();
    for (int o = tid; o < DIM; o += 256) {
      const float* w = Wq + o * DIM;
      float acc = 0.f;
      for (int k = 0; k < DIM; k += 4) {
        f32x4 a = *(const f32x4*)&qs[k];
        f32x4 b = *(const f32x4*)&w[k];
        acc += a.x * b.x + a.y * b.y + a.z * b.z + a.w * b.w;
      }
      q_out[blk * DIM + o] = acc + bq[o];
    }
  } else {
    const int c = blk - 64;
    const int flat = c * 4096 + tid * 16;
    const int o = flat >> 9, k0 = flat & 511;
    const int t = k0 >> 5, kk = k0 & 31;
    u16* dst = Wrbt + t * 16384 + o * 32 + kk;
#pragma unroll
    for (int i = 0; i < 4; ++i) {
      f32x4 a = *(const f32x4*)&Wr[flat + i * 4];
      s16x4 o4;
      o4.x = (short)f2bf(a.x); o4.y = (short)f2bf(a.y);
      o4.z = (short)f2bf(a.z); o4.w = (short)f2bf(a.w);
      *(s16x4*)&dst[i * 4] = o4;
    }
  }
}

// ---------- fused: ref-slab transpose (in-block) + GEMM + epilogue ----------
// grid (64 b fastest, 64 lc): co-resident same-lc blocks read a dense 4MB region.
// Block = 512o x 32l: 8 waves, each 64o x 32l (acc[4][2]). Stage 32 ref rows
// (f32 2KB contiguous each, nontemporal) -> cvt -> swizzled LDS (pitch-65
// 16B units, ul ^ (row&7)<<2; verified in rounds 5-7). K-loop = round-7's
// proven structure + depth-2 static A prefetch (covers ~200cy L2 latency).
__global__ __launch_bounds__(512, 3) void gemm_fused(
    const float* __restrict__ ref, const u16* __restrict__ Wrbt,
    const float* __restrict__ q, const float* __restrict__ br,
    const float* __restrict__ v, float* __restrict__ e_out,
    float* __restrict__ logits) {
  __shared__ u16 Bs[32 * 520];    // 33,280 B (65 units x 16B per row)
  __shared__ float u_lds[8][32];

  const int b = blockIdx.x, lc = blockIdx.y;
  const int l0 = lc * 32;
  const int tid = threadIdx.x, lane = tid & 63, w = tid >> 6;
  const int rr = lane & 15, kg = lane >> 4;

  // ---- stage: 32 rows x 512 f32 -> bf16 LDS (8 passes x 4 rows) ----
#pragma unroll
  for (int p = 0; p < 8; ++p) {
    const int row = p * 4 + (tid >> 7);
    const int col4 = tid & 127;
    f32x4 a = __builtin_nontemporal_load(
        (const f32x4*)&ref[((size_t)(l0 + row) * 64 + b) * 512 + col4 * 4]);
    s16x4 o4;
    o4.x = (short)f2bf(a.x); o4.y = (short)f2bf(a.y);
    o4.z = (short)f2bf(a.z); o4.w = (short)f2bf(a.w);
    const int unit = row * 65 + ((col4 >> 1) ^ ((row & 7) << 2));
    *(s16x4*)&Bs[(unit << 3) + ((col4 & 1) << 2)] = o4;
  }
  __syncthreads();

  const u16* ap = Wrbt + (w * 64 + rr) * 32 + kg * 8;

  f32x4 acc[4][2];
#pragma unroll
  for (int fm = 0; fm < 4; ++fm)
#pragma unroll
    for (int fn = 0; fn < 2; ++fn) acc[fm][fn] = (f32x4){0.f, 0.f, 0.f, 0.f};

  // depth-2 static A double-buffer (fully unrolled -> no register indexing)
  s16x8 A0[4], A1[4];
#pragma unroll
  for (int fm = 0; fm < 4; ++fm) {
    A0[fm] = *(const s16x8*)(ap + 0 * 16384 + fm * 512);
    A1[fm] = *(const s16x8*)(ap + 1 * 16384 + fm * 512);
  }

#pragma unroll
  for (int t = 0; t < 16; ++t) {
    s16x8 bf[2];
#pragma unroll
    for (int fn = 0; fn < 2; ++fn) {
      const int row = fn * 16 + rr;
      const int unit = row * 65 + ((t * 4 + kg) ^ ((row & 7) << 2));
      bf[fn] = *(const s16x8*)&Bs[unit << 3];
    }
    if (t & 1) {
#pragma unroll
      for (int fm = 0; fm < 4; ++fm)
#pragma unroll
        for (int fn = 0; fn < 2; ++fn)
          acc[fm][fn] = __builtin_amdgcn_mfma_f32_16x16x32_bf16(bf[fn], A1[fm], acc[fm][fn], 0, 0, 0);
      if (t + 2 < 16)
#pragma unroll
        for (int fm = 0; fm < 4; ++fm)
          A1[fm] = *(const s16x8*)(ap + (t + 2) * 16384 + fm * 512);
    } else {
#pragma unroll
      for (int fm = 0; fm < 4; ++fm)
#pragma unroll
        for (int fn = 0; fn < 2; ++fn)
          acc[fm][fn] = __builtin_amdgcn_mfma_f32_16x16x32_bf16(bf[fn], A0[fm], acc[fm][fn], 0, 0, 0);
      if (t + 2 < 16)
#pragma unroll
        for (int fm = 0; fm < 4; ++fm)
          A0[fm] = *(const s16x8*)(ap + (t + 2) * 16384 + fm * 512);
    }
  }

  // ---- epilogue: e = acc + br ; u = sum_o v * tanh(acc + q + br) ----
  f32x4 usA[2];
#pragma unroll
  for (int fn = 0; fn < 2; ++fn) usA[fn] = (f32x4){0.f, 0.f, 0.f, 0.f};
#pragma unroll
  for (int fm = 0; fm < 4; ++fm) {
    const int o = w * 64 + fm * 16 + rr;
    const float brv = br[o];
    const float qv = q[b * DIM + o] + brv;
    const float vv = v[o];
    const size_t erow = ((size_t)(b * DIM + o)) * L_;
#pragma unroll
    for (int fn = 0; fn < 2; ++fn) {
      const int lb = l0 + fn * 16 + kg * 4;
      f32x4 a = acc[fm][fn];
      f32x4 ev = a + brv;
      *(f32x4*)&e_out[erow + lb] = ev;
      f32x4 th;
      th.x = tanh_fast(a.x + qv);
      th.y = tanh_fast(a.y + qv);
      th.z = tanh_fast(a.z + qv);
      th.w = tanh_fast(a.w + qv);
      usA[fn] += vv * th;
    }
  }
#pragma unroll
  for (int fn = 0; fn < 2; ++fn) {
    f32x4 us = usA[fn];
#pragma unroll
    for (int msk = 1; msk <= 8; msk <<= 1) {  // reduce over rr (o dim)
      us.x += __shfl_xor(us.x, msk);
      us.y += __shfl_xor(us.y, msk);
      us.z += __shfl_xor(us.z, msk);
      us.w += __shfl_xor(us.w, msk);
    }
    if (rr == 0)
      *(f32x4*)&u_lds[w][fn * 16 + kg * 4] = us;
  }
  __syncthreads();
  if (tid < 32) {
    float s = 0.f;
#pragma unroll
    for (int ww = 0; ww < 8; ++ww) s += u_lds[ww][tid];
    logits[(size_t)b * L_ + l0 + tid] = s;
  }
}

extern "C" void kernel_launch(void* const* d_in, const int* in_sizes, int n_in,
                              void* d_out, int out_size, void* d_ws, size_t ws_size,
                              hipStream_t stream) {
  const float* query = (const float*)d_in[0];
  const float* ref   = (const float*)d_in[1];
  const float* Wq    = (const float*)d_in[2];
  const float* bq    = (const float*)d_in[3];
  const float* Wr    = (const float*)d_in[4];
  const float* br    = (const float*)d_in[5];
  const float* v     = (const float*)d_in[6];

  float* e_out  = (float*)d_out;
  float* logits = e_out + (size_t)B_ * DIM * L_;  // 67108864

  char* ws = (char*)d_ws;
  u16*   Wrbt = (u16*)ws;               // 512 KB [16][512][32]
  float* q    = (float*)(ws + 524288);  // 128 KB

  prep_kernel<<<128, 256, 0, stream>>>(query, Wq, bq, Wr, q, Wrbt);
  gemm_fused<<<dim3(64, 64), 512, 0, stream>>>(ref, Wrbt, q, br, v, e_out, logits);
}

// Round 9
// 233.978 us; speedup vs baseline: 1.6975x; 1.0354x over previous
//
#include <hip/hip_runtime.h>

#define DIM 512
#define B_  64
#define L_  2048

typedef unsigned short u16;
typedef float f32x4 __attribute__((ext_vector_type(4)));
typedef short s16x8 __attribute__((ext_vector_type(8)));
typedef short s16x4 __attribute__((ext_vector_type(4)));

__device__ __forceinline__ u16 f2bf(float f) {
  union { float f; unsigned u; } x{f};
  unsigned r = x.u + 0x7FFFu + ((x.u >> 16) & 1u);
  return (u16)(r >> 16);
}

__device__ __forceinline__ float tanh_fast(float x) {
  float e2 = __expf(2.0f * x);
  return 1.0f - 2.0f / (e2 + 1.0f);
}

// ---------- prep: q = query @ Wq^T + bq ; Wr -> bf16 transposed [t][o][32k] ----------
__global__ __launch_bounds__(256) void prep_kernel(
    const float* __restrict__ query, const float* __restrict__ Wq,
    const float* __restrict__ bq, const float* __restrict__ Wr,
    float* __restrict__ q_out, u16* __restrict__ Wrbt) {
  const int blk = blockIdx.x;
  const int tid = threadIdx.x;
  if (blk < 64) {
    __shared__ float qs[DIM];
    for (int i = tid; i < DIM; i += 256) qs[i] = query[blk * DIM + i];
    __syncthreads();
    for (int o = tid; o < DIM; o += 256) {
      const float* w = Wq + o * DIM;
      float acc = 0.f;
      for (int k = 0; k < DIM; k += 4) {
        f32x4 a = *(const f32x4*)&qs[k];
        f32x4 b = *(const f32x4*)&w[k];
        acc += a.x * b.x + a.y * b.y + a.z * b.z + a.w * b.w;
      }
      q_out[blk * DIM + o] = acc + bq[o];
    }
  } else {
    const int c = blk - 64;
    const int flat = c * 4096 + tid * 16;
    const int o = flat >> 9, k0 = flat & 511;
    const int t = k0 >> 5, kk = k0 & 31;
    u16* dst = Wrbt + t * 16384 + o * 32 + kk;
#pragma unroll
    for (int i = 0; i < 4; ++i) {
      f32x4 a = *(const f32x4*)&Wr[flat + i * 4];
      s16x4 o4;
      o4.x = (short)f2bf(a.x); o4.y = (short)f2bf(a.y);
      o4.z = (short)f2bf(a.z); o4.w = (short)f2bf(a.w);
      *(s16x4*)&dst[i * 4] = o4;
    }
  }
}

// ---------- fused: ref-slab transpose (in-block) + GEMM + epilogue ----------
// grid (64 b fastest, 64 lc). Block = 512o x 32l: 8 waves, each 64o x 32l
// (acc[4][2]). VGPR<=64 via __launch_bounds__(512,8): 4 blocks/CU, 32 waves/CU
// -- TLP covers the L2/HBM latency the compiler won't pipeline at source level.
__global__ __launch_bounds__(512, 8) void gemm_fused(
    const float* __restrict__ ref, const u16* __restrict__ Wrbt,
    const float* __restrict__ q, const float* __restrict__ br,
    const float* __restrict__ v, float* __restrict__ e_out,
    float* __restrict__ logits) {
  __shared__ u16 Bs[32 * 520];    // 33,280 B (65 units x 16B per row)
  __shared__ float u_lds[8][32];

  const int b = blockIdx.x, lc = blockIdx.y;
  const int l0 = lc * 32;
  const int tid = threadIdx.x, lane = tid & 63, w = tid >> 6;
  const int rr = lane & 15, kg = lane >> 4;

  // ---- stage: issue all 8 HBM loads first, then cvt + swizzled ds_write ----
  f32x4 sreg[8];
#pragma unroll
  for (int p = 0; p < 8; ++p) {
    const int row = p * 4 + (tid >> 7);
    const int col4 = tid & 127;
    sreg[p] = __builtin_nontemporal_load(
        (const f32x4*)&ref[((size_t)(l0 + row) * 64 + b) * 512 + col4 * 4]);
  }
#pragma unroll
  for (int p = 0; p < 8; ++p) {
    const int row = p * 4 + (tid >> 7);
    const int col4 = tid & 127;
    s16x4 o4;
    o4.x = (short)f2bf(sreg[p].x); o4.y = (short)f2bf(sreg[p].y);
    o4.z = (short)f2bf(sreg[p].z); o4.w = (short)f2bf(sreg[p].w);
    const int unit = row * 65 + ((col4 >> 1) ^ ((row & 7) << 2));
    *(s16x4*)&Bs[(unit << 3) + ((col4 & 1) << 2)] = o4;
  }
  __syncthreads();

  const u16* ap = Wrbt + (w * 64 + rr) * 32 + kg * 8;

  f32x4 acc[4][2];
#pragma unroll
  for (int fm = 0; fm < 4; ++fm)
#pragma unroll
    for (int fn = 0; fn < 2; ++fn) acc[fm][fn] = (f32x4){0.f, 0.f, 0.f, 0.f};

  // depth-2 static A double-buffer (compiler may sink under reg cap; TLP covers)
  s16x8 A0[4], A1[4];
#pragma unroll
  for (int fm = 0; fm < 4; ++fm) {
    A0[fm] = *(const s16x8*)(ap + 0 * 16384 + fm * 512);
    A1[fm] = *(const s16x8*)(ap + 1 * 16384 + fm * 512);
  }

#pragma unroll
  for (int t = 0; t < 16; ++t) {
    s16x8 bf[2];
#pragma unroll
    for (int fn = 0; fn < 2; ++fn) {
      const int row = fn * 16 + rr;
      const int unit = row * 65 + ((t * 4 + kg) ^ ((row & 7) << 2));
      bf[fn] = *(const s16x8*)&Bs[unit << 3];
    }
    if (t & 1) {
#pragma unroll
      for (int fm = 0; fm < 4; ++fm)
#pragma unroll
        for (int fn = 0; fn < 2; ++fn)
          acc[fm][fn] = __builtin_amdgcn_mfma_f32_16x16x32_bf16(bf[fn], A1[fm], acc[fm][fn], 0, 0, 0);
      if (t + 2 < 16)
#pragma unroll
        for (int fm = 0; fm < 4; ++fm)
          A1[fm] = *(const s16x8*)(ap + (t + 2) * 16384 + fm * 512);
    } else {
#pragma unroll
      for (int fm = 0; fm < 4; ++fm)
#pragma unroll
        for (int fn = 0; fn < 2; ++fn)
          acc[fm][fn] = __builtin_amdgcn_mfma_f32_16x16x32_bf16(bf[fn], A0[fm], acc[fm][fn], 0, 0, 0);
      if (t + 2 < 16)
#pragma unroll
        for (int fm = 0; fm < 4; ++fm)
          A0[fm] = *(const s16x8*)(ap + (t + 2) * 16384 + fm * 512);
    }
  }

  // ---- epilogue: e = acc + br ; u = sum_o v * tanh(acc + q + br) ----
  f32x4 usA[2];
#pragma unroll
  for (int fn = 0; fn < 2; ++fn) usA[fn] = (f32x4){0.f, 0.f, 0.f, 0.f};
#pragma unroll
  for (int fm = 0; fm < 4; ++fm) {
    const int o = w * 64 + fm * 16 + rr;
    const float brv = br[o];
    const float qv = q[b * DIM + o] + brv;
    const float vv = v[o];
    const size_t erow = ((size_t)(b * DIM + o)) * L_;
#pragma unroll
    for (int fn = 0; fn < 2; ++fn) {
      const int lb = l0 + fn * 16 + kg * 4;
      f32x4 a = acc[fm][fn];
      f32x4 ev = a + brv;
      *(f32x4*)&e_out[erow + lb] = ev;
      f32x4 th;
      th.x = tanh_fast(a.x + qv);
      th.y = tanh_fast(a.y + qv);
      th.z = tanh_fast(a.z + qv);
      th.w = tanh_fast(a.w + qv);
      usA[fn] += vv * th;
    }
  }
#pragma unroll
  for (int fn = 0; fn < 2; ++fn) {
    f32x4 us = usA[fn];
#pragma unroll
    for (int msk = 1; msk <= 8; msk <<= 1) {  // reduce over rr (o dim)
      us.x += __shfl_xor(us.x, msk);
      us.y += __shfl_xor(us.y, msk);
      us.z += __shfl_xor(us.z, msk);
      us.w += __shfl_xor(us.w, msk);
    }
    if (rr == 0)
      *(f32x4*)&u_lds[w][fn * 16 + kg * 4] = us;
  }
  __syncthreads();
  if (tid < 32) {
    float s = 0.f;
#pragma unroll
    for (int ww = 0; ww < 8; ++ww) s += u_lds[ww][tid];
    logits[(size_t)b * L_ + l0 + tid] = s;
  }
}

extern "C" void kernel_launch(void* const* d_in, const int* in_sizes, int n_in,
                              void* d_out, int out_size, void* d_ws, size_t ws_size,
                              hipStream_t stream) {
  const float* query = (const float*)d_in[0];
  const float* ref   = (const float*)d_in[1];
  const float* Wq    = (const float*)d_in[2];
  const float* bq    = (const float*)d_in[3];
  const float* Wr    = (const float*)d_in[4];
  const float* br    = (const float*)d_in[5];
  const float* v     = (const float*)d_in[6];

  float* e_out  = (float*)d_out;
  float* logits = e_out + (size_t)B_ * DIM * L_;  // 67108864

  char* ws = (char*)d_ws;
  u16*   Wrbt = (u16*)ws;               // 512 KB [16][512][32]
  float* q    = (float*)(ws + 524288);  // 128 KB

  prep_kernel<<<128, 256, 0, stream>>>(query, Wq, bq, Wr, q, Wrbt);
  gemm_fused<<<dim3(64, 64), 512, 0, stream>>>(ref, Wrbt, q, br, v, e_out, logits);
}